// Round 2
// baseline (256.844 us; speedup 1.0000x reference)
//
#include <hip/hip_runtime.h>

// Batched Kalman predict: x_hat = Ap x ; P_hat = Ap P Ap^T + Q
//
// 8 threads per element, one P-row per thread -> every global access from a
// wave covers a contiguous 2KB span. Cross-row mixing (left-multiply by Ap)
// staged through LDS *within one wave* (8-lane groups): no block barrier.
//
// EPT=4: each thread handles 4 elements; ALL P/x loads for the 4 elements are
// issued before any compute -> 16 dwordx4/lane (16KB/wave) in flight, 8x the
// memory-level parallelism of the 1-element version, and the wave prologue
// (Ap/sigma/apr loads, address setup) is amortized 4x. Kernel was at 3.8 TB/s
// vs ~6.5 TB/s achievable: latency/MLP-bound, not VALU- or BW-bound.
//
// Ap = triu(relu(A)) is precomputed once by a tiny setup kernel into g_cst:
//   [0..35]   packed triu rows (row l: 8-l values)  -> uniform scalar loads
//   [36..43]  per-row sigma (sp,sp,sp,sp,sv,sv,sv,sv)
//   [48..111] full 8x8 Ap row-major                 -> per-lane row r fetch
//
// LDS layout: element stride 100 dwords (== 4 mod 32), row stride 12 dwords.
// Read instruction (fixed j): bank starts = (4*d + 12*j) mod 32, d=0..7 within
// a wave -> 8 distinct starts, all 32 banks, conflict-free b128. The slot is
// reused across the 4 iterations (same-wave DS ops are pipeline-ordered; reads
// of iter i are consumed before iter i+1's write issues).

#define ROW_STRIDE 12
#define ELEM_STRIDE 100
#define SLOTS 32             // 256 threads / 8 rows
#define EPT 4                // elements per thread

__device__ __align__(16) float g_cst[112];

__global__ void kalman_setup_kernel(const float* __restrict__ A,
                                    const float* __restrict__ sigp_ptr,
                                    const float* __restrict__ sigv_ptr)
{
    int t = threadIdx.x;
    if (t < 64) {
        int l = t >> 3, k = t & 7;
        float a = fmaxf(A[t], 0.0f);        // relu
        if (k < l) a = 0.0f;                // triu
        g_cst[48 + t] = a;                  // full row-major Ap
        if (k >= l) {
            int off = l * 8 - (l * (l - 1)) / 2;   // packed-row offset
            g_cst[off + (k - l)] = a;
        }
    }
    if (t < 8) g_cst[36 + t] = (t < 4) ? sigp_ptr[0] : sigv_ptr[0];
}

__global__ __launch_bounds__(256) void kalman_predict_kernel(
    const float* __restrict__ x,
    const float* __restrict__ P,
    float* __restrict__ x_hat,
    float* __restrict__ P_hat,
    int B)
{
    __shared__ float lds_m[SLOTS * ELEM_STRIDE];

    int r   = threadIdx.x & 7;       // row within element
    int e_l = threadIdx.x >> 3;      // element slot within block (0..31)
    int eb  = blockIdx.x * (SLOTS * EPT);  // first element of this block

    // ---- prefetch ALL P rows + x vectors for EPT elements (16 dwordx4) ----
    float4 pA[EPT], pB[EPT], xA[EPT], xB[EPT];
    int ev[EPT];
#pragma unroll
    for (int i = 0; i < EPT; ++i) {
        int e = eb + i * SLOTS + e_l;
        ev[i] = e;
        unsigned ec = (unsigned)((e < B) ? e : (B - 1));   // clamp loads
        const float4* prow = (const float4*)(P + (size_t)ec * 64u + (unsigned)r * 8u);
        pA[i] = prow[0];
        pB[i] = prow[1];
        const float4* xrow = (const float4*)(x + (size_t)ec * 8u);
        xA[i] = xrow[0];
        xB[i] = xrow[1];
    }

    // ---- uniform packed triu(Ap) -> scalar regs; per-lane row r; sigma ----
    float apk[36];
#pragma unroll
    for (int t = 0; t < 36; ++t) apk[t] = g_cst[t];

    const float4* arow = (const float4*)(g_cst + 48 + r * 8);
    float4 a0 = arow[0], a1 = arow[1];
    float apr[8] = {a0.x, a0.y, a0.z, a0.w, a1.x, a1.y, a1.z, a1.w};
    float sig = g_cst[36 + r];

    float* slot = lds_m + e_l * ELEM_STRIDE + r * ROW_STRIDE;
    const float* ebase = lds_m + e_l * ELEM_STRIDE;

#pragma unroll
    for (int i = 0; i < EPT; ++i) {
        float p[8] = {pA[i].x, pA[i].y, pA[i].z, pA[i].w,
                      pB[i].x, pB[i].y, pB[i].z, pB[i].w};
        float xv[8] = {xA[i].x, xA[i].y, xA[i].z, xA[i].w,
                       xB[i].x, xB[i].y, xB[i].z, xB[i].w};

        // ---- step 1: M row r = P row r * Ap^T (triu: 36 FMAs) ----
        float m[8];
        {
            int idx = 0;
#pragma unroll
            for (int l = 0; l < 8; ++l) {
                float s = 0.0f;
#pragma unroll
                for (int k = l; k < 8; ++k) s = fmaf(apk[idx + (k - l)], p[k], s);
                m[l] = s;
                idx += 8 - l;
            }
        }

        // ---- stage M row in LDS (consumed only by this wave's 8-lane group) ----
        ((float4*)slot)[0] = make_float4(m[0], m[1], m[2], m[3]);
        ((float4*)(slot + 4))[0] = make_float4(m[4], m[5], m[6], m[7]);
        asm volatile("s_waitcnt lgkmcnt(0)" ::: "memory");  // intra-wave visibility

        // ---- Q diag entry for row r ----
        float hv = (r & 1) ? xv[3] : xv[2];
        float q = hv * sig;
        q = q * q;

        // ---- x_hat row r ----
        float xh = 0.0f;
#pragma unroll
        for (int j = 0; j < 8; ++j) xh = fmaf(apr[j], xv[j], xh);

        // ---- step 2: out[l] = sum_j apr[j] * M[j][l] + (l==r)*q ----
        float out[8];
#pragma unroll
        for (int l = 0; l < 8; ++l) out[l] = (l == r) ? q : 0.0f;
#pragma unroll
        for (int j = 0; j < 8; ++j) {
            const float4* mr = (const float4*)(ebase + j * ROW_STRIDE);
            float4 ma = mr[0], mb = mr[1];
            float mj[8] = {ma.x, ma.y, ma.z, ma.w, mb.x, mb.y, mb.z, mb.w};
#pragma unroll
            for (int l = 0; l < 8; ++l) out[l] = fmaf(apr[j], mj[l], out[l]);
        }
        // reads above are consumed before the next iteration's ds_write issues
        // (same-wave DS pipeline order + lgkmcnt waits on the FMA operands)

        // ---- stores: x_hat 4B/lane contiguous; P_hat rows contiguous 2KB ----
        if (ev[i] < B) {
            unsigned e = (unsigned)ev[i];
            x_hat[(size_t)e * 8u + r] = xh;
            float4* po = (float4*)(P_hat + (size_t)e * 64u + (unsigned)r * 8u);
            po[0] = make_float4(out[0], out[1], out[2], out[3]);
            po[1] = make_float4(out[4], out[5], out[6], out[7]);
        }
    }
}

extern "C" void kernel_launch(void* const* d_in, const int* in_sizes, int n_in,
                              void* d_out, int out_size, void* d_ws, size_t ws_size,
                              hipStream_t stream) {
    const float* x  = (const float*)d_in[0];
    const float* P  = (const float*)d_in[1];
    const float* A  = (const float*)d_in[2];
    const float* sp = (const float*)d_in[3];
    const float* sv = (const float*)d_in[4];

    int B = in_sizes[0] / 8;           // x is (B, 8, 1)
    float* x_hat = (float*)d_out;      // B*8 floats
    float* P_hat = (float*)d_out + (size_t)B * 8;  // B*64 floats

    kalman_setup_kernel<<<1, 64, 0, stream>>>(A, sp, sv);

    int elems_per_block = SLOTS * EPT;
    int grid = (B + elems_per_block - 1) / elems_per_block;
    kalman_predict_kernel<<<grid, 256, 0, stream>>>(x, P, x_hat, P_hat, B);
}

// Round 4
// 254.358 us; speedup vs baseline: 1.0098x; 1.0098x over previous
//
#include <hip/hip_runtime.h>

// Batched Kalman predict: x_hat = Ap x ; P_hat = Ap P Ap^T + Q
//
// 8 threads per element, one P-row per thread -> every global access from a
// wave covers a contiguous 2KB span. Cross-row mixing (left-multiply by Ap)
// staged through LDS *within one wave* (8-lane groups): no block barrier.
//
// R4 (= R3 intent, types fixed): ALL global traffic nontemporal. The harness
// poison-fill (576 MB) guarantees output lines are not cache-resident, so
// regular stores would write-allocate: each P_hat line fetched from HBM before
// being overwritten (+144 MB hidden FETCH -> 432 MB total, matching the
// observed ~75 us at 6.3 TB/s). NT stores bypass allocation; NT loads keep the
// never-reused P/x streams from polluting L2/L3.
// __builtin_nontemporal_* requires native vector types, not HIP_vector_type:
// use a clang ext_vector_type(4) alias (fx4).
//
// Ap = triu(relu(A)) precomputed once by a tiny setup kernel into g_cst:
//   [0..35]   packed triu rows (row l: 8-l values)  -> uniform loads
//   [36..43]  per-row sigma (sp,sp,sp,sp,sv,sv,sv,sv)
//   [48..111] full 8x8 Ap row-major                 -> per-lane row r fetch
//
// LDS layout: element stride 100 dwords (== 4 mod 32), row stride 12 dwords.
// Read instruction (fixed j): bank starts = (4*d + 12*j) mod 32, d=0..7 within
// a wave -> 8 distinct starts, all 32 banks, conflict-free b128.

#define ROW_STRIDE 12
#define ELEM_STRIDE 100
#define SLOTS 32             // 256 threads / 8 rows

typedef float fx4 __attribute__((ext_vector_type(4)));

__device__ __align__(16) float g_cst[112];

__global__ void kalman_setup_kernel(const float* __restrict__ A,
                                    const float* __restrict__ sigp_ptr,
                                    const float* __restrict__ sigv_ptr)
{
    int t = threadIdx.x;
    if (t < 64) {
        int l = t >> 3, k = t & 7;
        float a = fmaxf(A[t], 0.0f);        // relu
        if (k < l) a = 0.0f;                // triu
        g_cst[48 + t] = a;                  // full row-major Ap
        if (k >= l) {
            int off = l * 8 - (l * (l - 1)) / 2;   // packed-row offset
            g_cst[off + (k - l)] = a;
        }
    }
    if (t < 8) g_cst[36 + t] = (t < 4) ? sigp_ptr[0] : sigv_ptr[0];
}

__global__ __launch_bounds__(256) void kalman_predict_kernel(
    const float* __restrict__ x,
    const float* __restrict__ P,
    float* __restrict__ x_hat,
    float* __restrict__ P_hat,
    int B)
{
    __shared__ float lds_m[SLOTS * ELEM_STRIDE];

    int tid = blockIdx.x * blockDim.x + threadIdx.x;
    int e = tid >> 3;           // batch element
    int r = tid & 7;            // row within element
    int e_l = threadIdx.x >> 3; // element slot within block (0..31)

    bool valid = (e < B);
    int e_c = valid ? e : (B - 1);   // clamp loads; stores predicated

    // ---- own P row, nontemporal (stream, no L2/L3 pollution) ----
    unsigned poff = (unsigned)e_c * 64u + (unsigned)r * 8u;
    const fx4* prow = (const fx4*)(P + poff);
    fx4 pa = __builtin_nontemporal_load(prow);
    fx4 pb = __builtin_nontemporal_load(prow + 1);
    float p[8] = {pa.x, pa.y, pa.z, pa.w, pb.x, pb.y, pb.z, pb.w};

    // ---- own x (8 lanes share the same 32B -> single-line broadcast) ----
    const fx4* xrow = (const fx4*)(x + (unsigned)e_c * 8u);
    fx4 x0 = __builtin_nontemporal_load(xrow);
    fx4 x1 = __builtin_nontemporal_load(xrow + 1);
    float xv[8] = {x0.x, x0.y, x0.z, x0.w, x1.x, x1.y, x1.z, x1.w};

    // ---- uniform packed triu(Ap); per-lane row r; sigma (L2-hot) ----
    float apk[36];
#pragma unroll
    for (int t = 0; t < 36; ++t) apk[t] = g_cst[t];

    const fx4* arow = (const fx4*)(g_cst + 48 + r * 8);
    fx4 a0 = arow[0], a1 = arow[1];
    float apr[8] = {a0.x, a0.y, a0.z, a0.w, a1.x, a1.y, a1.z, a1.w};
    float sig = g_cst[36 + r];

    // ---- step 1: M row r = P row r * Ap^T (triu: 36 FMAs) ----
    float m[8];
    {
        int idx = 0;
#pragma unroll
        for (int l = 0; l < 8; ++l) {
            float s = 0.0f;
#pragma unroll
            for (int k = l; k < 8; ++k) s = fmaf(apk[idx + (k - l)], p[k], s);
            m[l] = s;
            idx += 8 - l;
        }
    }

    // ---- stage M row in LDS (consumed only by this wave's 8-lane group) ----
    float* slot = lds_m + e_l * ELEM_STRIDE + r * ROW_STRIDE;
    ((fx4*)slot)[0] = (fx4){m[0], m[1], m[2], m[3]};
    ((fx4*)(slot + 4))[0] = (fx4){m[4], m[5], m[6], m[7]};
    asm volatile("s_waitcnt lgkmcnt(0)" ::: "memory");  // intra-wave visibility

    // ---- Q diag entry for row r ----
    float hv = (r & 1) ? xv[3] : xv[2];
    float q = hv * sig;
    q = q * q;

    // ---- x_hat row r ----
    float xh = 0.0f;
#pragma unroll
    for (int j = 0; j < 8; ++j) xh = fmaf(apr[j], xv[j], xh);

    // ---- step 2: out[l] = sum_j apr[j] * M[j][l] + (l==r)*q ----
    float out[8];
#pragma unroll
    for (int l = 0; l < 8; ++l) out[l] = (l == r) ? q : 0.0f;

    const float* ebase = lds_m + e_l * ELEM_STRIDE;
#pragma unroll
    for (int j = 0; j < 8; ++j) {
        const fx4* mr = (const fx4*)(ebase + j * ROW_STRIDE);
        fx4 ma = mr[0], mb = mr[1];
        float mj[8] = {ma.x, ma.y, ma.z, ma.w, mb.x, mb.y, mb.z, mb.w};
#pragma unroll
        for (int l = 0; l < 8; ++l) out[l] = fmaf(apr[j], mj[l], out[l]);
    }

    // ---- nontemporal stores: no write-allocate/RFO on poisoned (uncached)
    //      output lines; wave spans stay contiguous 2KB ----
    if (valid) {
        __builtin_nontemporal_store(xh, x_hat + (size_t)e * 8u + r);
        fx4* po = (fx4*)(P_hat + (size_t)e * 64u + (unsigned)r * 8u);
        __builtin_nontemporal_store((fx4){out[0], out[1], out[2], out[3]}, po);
        __builtin_nontemporal_store((fx4){out[4], out[5], out[6], out[7]}, po + 1);
    }
}

extern "C" void kernel_launch(void* const* d_in, const int* in_sizes, int n_in,
                              void* d_out, int out_size, void* d_ws, size_t ws_size,
                              hipStream_t stream) {
    const float* x  = (const float*)d_in[0];
    const float* P  = (const float*)d_in[1];
    const float* A  = (const float*)d_in[2];
    const float* sp = (const float*)d_in[3];
    const float* sv = (const float*)d_in[4];

    int B = in_sizes[0] / 8;           // x is (B, 8, 1)
    float* x_hat = (float*)d_out;      // B*8 floats
    float* P_hat = (float*)d_out + (size_t)B * 8;  // B*64 floats

    kalman_setup_kernel<<<1, 64, 0, stream>>>(A, sp, sv);

    int threads = B * 8;
    int block = 256;
    int grid = (threads + block - 1) / block;
    kalman_predict_kernel<<<grid, block, 0, stream>>>(x, P, x_hat, P_hat, B);
}